// Round 1
// baseline (410.627 us; speedup 1.0000x reference)
//
#include <hip/hip_runtime.h>
#include <cstdint>
#include <cstddef>

#define M_DIM 8192
#define N_DIM 4096
#define K_DIM 4096

// fallback-path tile (128x128, verified)
#define BM 128
#define BN 128
#define BK 128

// fast-path 8-phase tile
#define BM2 256
#define BN2 256
#define BK2 128
#define NKT (K_DIM / BK2)   // 32

typedef int int32x4 __attribute__((ext_vector_type(4)));

// ws layout:
//   int32 header (64 KB):
//     [0] = flagA (1 -> source already packed int8, 0 -> widened int32)
//     [1] = flagB
//     [16 .. 16+N)      qb (shifted bias)
//     [16+N .. 16+2N)   int_scale
//     [16+2N .. 16+3N)  frac_bits
//   byte 65536:           A8  (M*K int8)  (only used when flagA==0)
//   byte 65536 + M*K:     W8  (N*K int8)  (only used when flagB==0)

typedef __attribute__((address_space(1))) const void* gas_cptr;
typedef __attribute__((address_space(3))) void* las_ptr;

__device__ __forceinline__ void async_copy16(const void* g, void* l) {
    __builtin_amdgcn_global_load_lds((gas_cptr)g, (las_ptr)l, 16, 0, 0);
}

__device__ __forceinline__ int32x4 pack16(const int* p) {
    const int32x4* v = (const int32x4*)p;
    int32x4 w0 = v[0], w1 = v[1], w2 = v[2], w3 = v[3];
    int32x4 r;
    r.x = (w0.x & 0xFF) | ((w0.y & 0xFF) << 8) | ((w0.z & 0xFF) << 16) | (w0.w << 24);
    r.y = (w1.x & 0xFF) | ((w1.y & 0xFF) << 8) | ((w1.z & 0xFF) << 16) | (w1.w << 24);
    r.z = (w2.x & 0xFF) | ((w2.y & 0xFF) << 8) | ((w2.z & 0xFF) << 16) | (w2.w << 24);
    r.w = (w3.x & 0xFF) | ((w3.y & 0xFF) << 8) | ((w3.z & 0xFF) << 16) | (w3.w << 24);
    return r;
}

__global__ void ql_detect_kernel(const int* a, const int* b, int* ws) {
    int t = threadIdx.x;  // 64 threads
    int fa = 0, fb = 0;
    for (int i = t; i < 4096; i += 64) {
        int va = a[i]; if (va > 127 || va < -128) fa = 1;
        int vb = b[i]; if (vb > 127 || vb < -128) fb = 1;
    }
    unsigned long long ba = __ballot(fa);
    unsigned long long bb = __ballot(fb);
    if (t == 0) { ws[0] = ba ? 1 : 0; ws[1] = bb ? 1 : 0; }
}

// Repack only needed when the source is widened int32; if already packed int8
// the GEMM/prep read the source directly (flag-selected), so just exit.
__global__ __launch_bounds__(256)
void ql_pack_kernel(const void* src, int* dst, const int* ws, int flag_idx, long ndw) {
    const int f8 = __builtin_amdgcn_readfirstlane(ws[flag_idx]);
    if (f8) return;                          // source already int8 — no copy needed
    const long stride = (long)gridDim.x * 256;
    for (long c = (long)blockIdx.x * 256 + threadIdx.x; c < ndw; c += stride) {
        int32x4 v = ((const int32x4*)src)[c];
        dst[c] = (v.x & 0xFF) | ((v.y & 0xFF) << 8) | ((v.z & 0xFF) << 16) | (v.w << 24);
    }
}

// Fast-path prep: rowsum + requant params from flag-selected int8 weights.
__global__ void ql_prep8_kernel(const void* worig, const int8_t* w8p, const int* qbias,
                                const float* wscale, int* ws) {
    const int fb = __builtin_amdgcn_readfirstlane(ws[1]);
    const int8_t* w8 = fb ? (const int8_t*)worig : w8p;

    const int lane = threadIdx.x & 63;
    const int wid  = threadIdx.x >> 6;
    const int n = blockIdx.x * 4 + wid;

    const int32x4* row = (const int32x4*)(w8 + (size_t)n * K_DIM);
    int s = 0;
    for (int c = lane; c < K_DIM / 16; c += 64) {
        int32x4 v = row[c];
#pragma unroll
        for (int j = 0; j < 4; ++j) {
            int w = (j == 0) ? v.x : (j == 1) ? v.y : (j == 2) ? v.z : v.w;
            s += (int)(int8_t)(w) + (int)(int8_t)(w >> 8)
               + (int)(int8_t)(w >> 16) + (w >> 24);
        }
    }
#pragma unroll
    for (int off = 32; off > 0; off >>= 1) s += __shfl_down(s, off, 64);

    if (lane == 0) {
        ws[16 + n] = qbias[n] + 3 * s;                       // qbias - rowsum*Zin, Zin=-3
        float folded = (0.05f * wscale[n]) / 0.1f;           // in (0,1)
        int fbits = (int)(7.0f - ceilf(log2f(folded)));
        int isc = (int)rintf(folded * exp2f((float)fbits));  // nearest-even == np.round
        ws[16 + N_DIM + n] = isc;
        ws[16 + 2 * N_DIM + n] = fbits;
    }
}

// Fallback prep (ws too small): reads original W, flag-based.
__global__ void ql_prep_kernel(const void* wptr, const int* qbias,
                               const float* wscale, int* ws) {
    const int lane = threadIdx.x & 63;
    const int wid  = threadIdx.x >> 6;
    const int n = blockIdx.x * 4 + wid;
    const int b8 = __builtin_amdgcn_readfirstlane(ws[1]);

    int s = 0;
    if (b8) {
        const int32x4* row = (const int32x4*)((const int8_t*)wptr + (size_t)n * K_DIM);
        for (int c = lane; c < K_DIM / 16; c += 64) {
            int32x4 v = row[c];
#pragma unroll
            for (int j = 0; j < 4; ++j) {
                int w = (j == 0) ? v.x : (j == 1) ? v.y : (j == 2) ? v.z : v.w;
                s += (int)(int8_t)(w) + (int)(int8_t)(w >> 8)
                   + (int)(int8_t)(w >> 16) + (w >> 24);
            }
        }
    } else {
        const int32x4* row = (const int32x4*)((const int*)wptr + (size_t)n * K_DIM);
        for (int c = lane; c < K_DIM / 4; c += 64) {
            int32x4 v = row[c];
            s += v.x + v.y + v.z + v.w;
        }
    }
#pragma unroll
    for (int off = 32; off > 0; off >>= 1) s += __shfl_down(s, off, 64);

    if (lane == 0) {
        ws[16 + n] = qbias[n] + 3 * s;
        float folded = (0.05f * wscale[n]) / 0.1f;
        int fbits = (int)(7.0f - ceilf(log2f(folded)));
        int isc = (int)rintf(folded * exp2f((float)fbits));
        ws[16 + N_DIM + n] = isc;
        ws[16 + 2 * N_DIM + n] = fbits;
    }
}

// Fallback epilogue (128x128 path): requantize acc tile and store int32.
__device__ __forceinline__ void ql_epilogue(int32x4 acc[4][4], const int* ws,
                                            int* out, int bm, int bn,
                                            int wm, int wn, int qm, int qh) {
    const int* qb  = ws + 16;
    const int* isc = ws + 16 + N_DIM;
    const int* fbt = ws + 16 + 2 * N_DIM;
#pragma unroll
    for (int j = 0; j < 4; ++j) {
        const int n_g = bn * BN + wn + j * 16 + qm;
        const int b0 = qb[n_g];
        const int s0 = isc[n_g];
        const int f0 = fbt[n_g];
#pragma unroll
        for (int i = 0; i < 4; ++i) {
            const int m_base = bm * BM + wm + i * 16 + qh * 4;
#pragma unroll
            for (int r = 0; r < 4; ++r) {
                int v = ((r == 0) ? acc[i][j].x : (r == 1) ? acc[i][j].y
                        : (r == 2) ? acc[i][j].z : acc[i][j].w) + b0;
                long long p = (long long)v * (long long)s0;
                int o = (int)(p >> f0) - 5;            // + OUTPUT_ZERO_POINT (-5)
                o = o < -128 ? -128 : (o > 127 ? 127 : o);
                out[(size_t)(m_base + r) * N_DIM + n_g] = o;
            }
        }
    }
}

// -------------------- fast path: 256x256 8-phase counted-vmcnt GEMM --------------------
// Half-tile = 128 rows x 128 B = 16 KB = 2 global_load_lds per thread (512 thr x 16 B x 2).
// Ring schedule per tile T (phases p1..p4, buffers cur = T&1):
//   p1 reads A0+B-lo  quadrant (mh0,nh0), stages T+1.A1 -> LA[cur^1]   (slot freed at T-1.p4)
//   p2 reads B-hi     quadrant (mh0,nh1), stages T+1.B1 -> LB[cur^1]   (slot freed at T-1.p4)
//   p3 reads A1       quadrant (mh1,nh0), stages T+2.A0 -> LA[cur]     (slot freed at T.p2)
//   p4 (no reads)     quadrant (mh1,nh1), stages T+2.B0 -> LB[cur]     (slot freed at T.p3)
// Checkpoint at tile top: vmcnt(4) leaves only next-tile A0/B0 (4 loads) in flight;
// everything older (all of tile T) is complete. Last tile drains vmcnt(0).
__device__ __forceinline__ void stage_half8(const int8_t* src, int row0, int tt,
                                            int h, int32x4* Lbuf, int t) {
    const int k0 = tt * BK2;
#pragma unroll
    for (int r = 0; r < 2; ++r) {
        const int c    = h * 1024 + r * 512 + t;      // chunk id within 2048-chunk buffer
        const int row  = c >> 3;                      // 0..255
        const int colg = (c & 7) ^ (row & 7);         // inverse swizzle on global source
        const size_t off = (size_t)(row0 + row) * K_DIM + k0 + colg * 16;
        async_copy16(src + off, &Lbuf[c]);
    }
}

__global__ __launch_bounds__(512, 2)
void ql_gemm8_kernel(const void* a0, const int8_t* a8,
                     const void* b0, const int8_t* w8,
                     const int* ws, int* out) {
    __shared__ int32x4 LA[2][2048];   // 2 x 32 KB
    __shared__ int32x4 LB[2][2048];   // 2 x 32 KB  (total 128 KB)

    const int fa = __builtin_amdgcn_readfirstlane(ws[0]);
    const int fb = __builtin_amdgcn_readfirstlane(ws[1]);
    const int8_t* aptr = fa ? (const int8_t*)a0 : a8;
    const int8_t* bptr = fb ? (const int8_t*)b0 : w8;

    const int t    = threadIdx.x;     // 512 threads = 8 waves
    const int lane = t & 63;
    const int wid  = t >> 6;          // 0..7
    const int wr   = wid >> 2;        // 0..1  M-half of block tile (128 rows each)
    const int wc   = wid & 3;         // 0..3  N-quarter (64 cols each)
    const int qm   = lane & 15;
    const int qh   = lane >> 4;

    const int bn = blockIdx.x;        // N/256 = 16
    const int bm = blockIdx.y;        // M/256 = 32
    const int arow0 = bm * BM2;
    const int brow0 = bn * BN2;

    int32x4 acc[8][4] = {};
    int32x4 af0[4][2], af1[4][2], bf0[2][2], bf1[2][2];

    // prologue: T0.{A0,B0,A1,B1}, T1.{A0,B0}  (12 loads/wave issued)
    stage_half8(aptr, arow0, 0, 0, &LA[0][0], t);
    stage_half8(bptr, brow0, 0, 0, &LB[0][0], t);
    stage_half8(aptr, arow0, 0, 1, &LA[0][0], t);
    stage_half8(bptr, brow0, 0, 1, &LB[0][0], t);
    stage_half8(aptr, arow0, 1, 0, &LA[1][0], t);
    stage_half8(bptr, brow0, 1, 0, &LB[1][0], t);

    for (int T = 0; T < NKT; ++T) {
        const int cur = T & 1;
        // tile checkpoint: all of tile T landed; next-tile A0/B0 may stay in flight
        if (T < NKT - 1) asm volatile("s_waitcnt vmcnt(4)");
        else             asm volatile("s_waitcnt vmcnt(0)");
        __builtin_amdgcn_s_barrier();

        // ---------------- phase 1: quadrant (mh=0, nh=0) ----------------
#pragma unroll
        for (int i = 0; i < 4; ++i) {
            const int ra = wr * 128 + i * 16 + qm;
#pragma unroll
            for (int s = 0; s < 2; ++s)
                af0[i][s] = LA[cur][ra * 8 + ((s * 4 + qh) ^ (ra & 7))];
        }
#pragma unroll
        for (int j = 0; j < 2; ++j) {
            const int rb = wc * 64 + j * 16 + qm;
#pragma unroll
            for (int s = 0; s < 2; ++s)
                bf0[j][s] = LB[cur][rb * 8 + ((s * 4 + qh) ^ (rb & 7))];
        }
        if (T + 1 < NKT) stage_half8(aptr, arow0, T + 1, 1, &LA[cur ^ 1][0], t);
        __builtin_amdgcn_s_barrier();
        __builtin_amdgcn_s_setprio(1);
#pragma unroll
        for (int s = 0; s < 2; ++s)
#pragma unroll
            for (int i = 0; i < 4; ++i)
#pragma unroll
                for (int j = 0; j < 2; ++j)
                    acc[i][j] = __builtin_amdgcn_mfma_i32_16x16x64_i8(
                        af0[i][s], bf0[j][s], acc[i][j], 0, 0, 0);
        __builtin_amdgcn_s_setprio(0);
        __builtin_amdgcn_s_barrier();

        // ---------------- phase 2: quadrant (mh=0, nh=1) ----------------
#pragma unroll
        for (int j = 0; j < 2; ++j) {
            const int rb = wc * 64 + (j + 2) * 16 + qm;
#pragma unroll
            for (int s = 0; s < 2; ++s)
                bf1[j][s] = LB[cur][rb * 8 + ((s * 4 + qh) ^ (rb & 7))];
        }
        if (T + 1 < NKT) stage_half8(bptr, brow0, T + 1, 1, &LB[cur ^ 1][0], t);
        __builtin_amdgcn_s_barrier();
        __builtin_amdgcn_s_setprio(1);
#pragma unroll
        for (int s = 0; s < 2; ++s)
#pragma unroll
            for (int i = 0; i < 4; ++i)
#pragma unroll
                for (int j = 0; j < 2; ++j)
                    acc[i][j + 2] = __builtin_amdgcn_mfma_i32_16x16x64_i8(
                        af0[i][s], bf1[j][s], acc[i][j + 2], 0, 0, 0);
        __builtin_amdgcn_s_setprio(0);
        __builtin_amdgcn_s_barrier();

        // ---------------- phase 3: quadrant (mh=1, nh=0) ----------------
#pragma unroll
        for (int i = 0; i < 4; ++i) {
            const int ra = wr * 128 + (i + 4) * 16 + qm;
#pragma unroll
            for (int s = 0; s < 2; ++s)
                af1[i][s] = LA[cur][ra * 8 + ((s * 4 + qh) ^ (ra & 7))];
        }
        if (T + 2 < NKT) stage_half8(aptr, arow0, T + 2, 0, &LA[cur][0], t);
        __builtin_amdgcn_s_barrier();
        __builtin_amdgcn_s_setprio(1);
#pragma unroll
        for (int s = 0; s < 2; ++s)
#pragma unroll
            for (int i = 0; i < 4; ++i)
#pragma unroll
                for (int j = 0; j < 2; ++j)
                    acc[i + 4][j] = __builtin_amdgcn_mfma_i32_16x16x64_i8(
                        af1[i][s], bf0[j][s], acc[i + 4][j], 0, 0, 0);
        __builtin_amdgcn_s_setprio(0);
        __builtin_amdgcn_s_barrier();

        // ---------------- phase 4: quadrant (mh=1, nh=1) ----------------
        if (T + 2 < NKT) stage_half8(bptr, brow0, T + 2, 0, &LB[cur][0], t);
        __builtin_amdgcn_s_barrier();
        __builtin_amdgcn_s_setprio(1);
#pragma unroll
        for (int s = 0; s < 2; ++s)
#pragma unroll
            for (int i = 0; i < 4; ++i)
#pragma unroll
                for (int j = 0; j < 2; ++j)
                    acc[i + 4][j + 2] = __builtin_amdgcn_mfma_i32_16x16x64_i8(
                        af1[i][s], bf1[j][s], acc[i + 4][j + 2], 0, 0, 0);
        __builtin_amdgcn_s_setprio(0);
        // phase-4 closing barrier == next-iteration checkpoint barrier
    }

    // epilogue: requantize + store
    const int* qb  = ws + 16;
    const int* isc = ws + 16 + N_DIM;
    const int* fbt = ws + 16 + 2 * N_DIM;
#pragma unroll
    for (int j = 0; j < 4; ++j) {
        const int n_g = bn * BN2 + wc * 64 + j * 16 + qm;
        const int b0r = qb[n_g];
        const int s0r = isc[n_g];
        const int f0r = fbt[n_g];
#pragma unroll
        for (int i = 0; i < 8; ++i) {
            const int m_base = bm * BM2 + wr * 128 + i * 16 + qh * 4;
#pragma unroll
            for (int r = 0; r < 4; ++r) {
                int v = ((r == 0) ? acc[i][j].x : (r == 1) ? acc[i][j].y
                        : (r == 2) ? acc[i][j].z : acc[i][j].w) + b0r;
                long long p = (long long)v * (long long)s0r;
                int o = (int)(p >> f0r) - 5;           // + OUTPUT_ZERO_POINT (-5)
                o = o < -128 ? -128 : (o > 127 ? 127 : o);
                out[(size_t)(m_base + r) * N_DIM + n_g] = o;
            }
        }
    }
}

// Fallback (ws too small): verified 128x128 kernel, packs in-loop.
__global__ __launch_bounds__(256)
void ql_gemm_fb_kernel(const void* aptr, const void* bptr, const int* ws, int* out) {
    __shared__ int32x4 Als[BM * BK / 16];
    __shared__ int32x4 Bls[BN * BK / 16];

    const int a8 = __builtin_amdgcn_readfirstlane(ws[0]);
    const int b8 = __builtin_amdgcn_readfirstlane(ws[1]);

    const int t    = threadIdx.x;
    const int lane = t & 63;
    const int wid  = t >> 6;
    const int bn = blockIdx.x;
    const int bm = blockIdx.y;

    const int wm = (wid >> 1) * 64;
    const int wn = (wid & 1) * 64;
    const int qm = lane & 15;
    const int qh = lane >> 4;

    int32x4 acc[4][4] = {};

    for (int kt = 0; kt < K_DIM / BK; ++kt) {
        __syncthreads();
        const int k0 = kt * BK;
#pragma unroll
        for (int r = 0; r < 4; ++r) {
            const int c    = r * 256 + t;
            const int row  = c >> 3;
            const int colg = (c & 7) ^ (row & 7);
            const size_t offA = (size_t)(bm * BM + row) * K_DIM + k0 + colg * 16;
            const size_t offB = (size_t)(bn * BN + row) * K_DIM + k0 + colg * 16;
            if (a8) async_copy16((const int8_t*)aptr + offA, &Als[c]);
            else    Als[c] = pack16((const int*)aptr + offA);
            if (b8) async_copy16((const int8_t*)bptr + offB, &Bls[c]);
            else    Bls[c] = pack16((const int*)bptr + offB);
        }
        __syncthreads();

#pragma unroll
        for (int s = 0; s < 2; ++s) {
            const int colk = s * 4 + qh;
            int32x4 af[4], bf[4];
#pragma unroll
            for (int i = 0; i < 4; ++i) {
                const int ra = wm + i * 16 + qm;
                const int rb = wn + i * 16 + qm;
                af[i] = Als[ra * 8 + (colk ^ (ra & 7))];
                bf[i] = Bls[rb * 8 + (colk ^ (rb & 7))];
            }
#pragma unroll
            for (int i = 0; i < 4; ++i)
#pragma unroll
                for (int j = 0; j < 4; ++j)
                    acc[i][j] = __builtin_amdgcn_mfma_i32_16x16x64_i8(
                        af[i], bf[j], acc[i][j], 0, 0, 0);
        }
    }
    ql_epilogue(acc, ws, out, bm, bn, wm, wn, qm, qh);
}

extern "C" void kernel_launch(void* const* d_in, const int* in_sizes, int n_in,
                              void* d_out, int out_size, void* d_ws, size_t ws_size,
                              hipStream_t stream) {
    const void* qin    = d_in[0];
    const void* qwt    = d_in[1];
    const int* qbias   = (const int*)d_in[2];
    const float* wscal = (const float*)d_in[3];
    int* ws  = (int*)d_ws;
    int* out = (int*)d_out;

    hipLaunchKernelGGL(ql_detect_kernel, dim3(1), dim3(64), 0, stream,
                       (const int*)qin, (const int*)qwt, ws);

    const size_t need = 65536 + (size_t)M_DIM * K_DIM + (size_t)N_DIM * K_DIM;
    if (ws_size >= need) {
        int8_t* a8 = (int8_t*)d_ws + 65536;
        int8_t* w8 = a8 + (size_t)M_DIM * K_DIM;
        const long ndwA = (long)M_DIM * K_DIM / 4;   // output dwords
        const long ndwW = (long)N_DIM * K_DIM / 4;
        hipLaunchKernelGGL(ql_pack_kernel, dim3((unsigned)(ndwW / (256 * 4))), dim3(256),
                           0, stream, qwt, (int*)w8, ws, 1, ndwW);
        hipLaunchKernelGGL(ql_pack_kernel, dim3((unsigned)(ndwA / (256 * 4))), dim3(256),
                           0, stream, qin, (int*)a8, ws, 0, ndwA);
        hipLaunchKernelGGL(ql_prep8_kernel, dim3(N_DIM / 4), dim3(256), 0, stream,
                           qwt, w8, qbias, wscal, ws);
        hipLaunchKernelGGL(ql_gemm8_kernel, dim3(N_DIM / BN2, M_DIM / BM2), dim3(512),
                           0, stream, qin, a8, qwt, w8, ws, out);
    } else {
        hipLaunchKernelGGL(ql_prep_kernel, dim3(N_DIM / 4), dim3(256), 0, stream,
                           qwt, qbias, wscal, ws);
        hipLaunchKernelGGL(ql_gemm_fb_kernel, dim3(N_DIM / BN, M_DIM / BM), dim3(256), 0, stream,
                           qin, qwt, ws, out);
    }
}